// Round 3
// baseline (21927.138 us; speedup 1.0000x reference)
//
#include <hip/hip_runtime.h>

#define NBLK 8
#define BROWS 131072
#define HDIM 512
#define EPSV 1e-5f
#define WROWS 64

typedef __bf16 bf16x8 __attribute__((ext_vector_type(8)));
typedef __bf16 bf16x4 __attribute__((ext_vector_type(4)));
typedef float f32x4 __attribute__((ext_vector_type(4)));

// packed net stream (elems): l0 16384 | 3 hidden x 262144 | head 16384
// layouts (unchanged; reinterpreted at use site):
//   l0     [w16][fb2][lane64][8]
//   hidden [w16][kt16][fb2][lane64][8]
//   head   [fb2][kt16][lane64][8]
#define PACK_NET 819200
#define PACK_H 16384
#define PACK_HEAD 802816

__device__ __forceinline__ float act_tanh_f(float x) {
  float e = __expf(x + x);
  return fmaf(-2.f, __builtin_amdgcn_rcpf(e + 1.f), 1.f);
}

template <int ACT>
__device__ __forceinline__ float apply_act(float v) {
  if (ACT == 1) return act_tanh_f(v);
  return fmaxf(v, 0.f);
}

// ---- one half-layer pass: MFMA rows [mRow0, mRow0+32) of the given layer,
//      with the PREVIOUS half's epilogue (act+pack+LDS-write to rows
//      [eRow0, eRow0+32)) interleaved one chunk per 2 kt steps.
//      Row-disjointness (mRow0 != eRow0) makes in-pass write||read safe.
template <int ACT, bool REV, bool DO_EPI>
__device__ __forceinline__ void hidden_pass(
    const __bf16* __restrict__ Wp, const float* __restrict__ biasE,
    __bf16* hb, f32x4 (&accM)[2][4], const f32x4 (&accE)[2][4],
    const int mRow0, const int eRow0, int w, int c, int quad, int lane) {
  const __bf16* wp = Wp + (size_t)(w * 2) * 16384 + lane * 8;
  const int msk = (c & 7) << 3;
#pragma unroll
  for (int rb = 0; rb < 2; ++rb)
#pragma unroll
    for (int ft = 0; ft < 4; ++ft) accM[rb][ft] = (f32x4){0.f, 0.f, 0.f, 0.f};
  bf16x8 br[2][4];
  {
    const int kt0 = REV ? 15 : 0;
#pragma unroll
    for (int ft = 0; ft < 4; ++ft)
      br[0][ft] = *(const bf16x8*)(wp + (ft >> 1) * 16384 + (ft & 1) * 512 + kt0 * 1024);
  }
#pragma unroll
  for (int i = 0; i < 16; ++i) {
    const int ktp = REV ? (15 - i) : i;
    if (i + 1 < 16) {
      const int ktn = REV ? (14 - i) : (i + 1);
#pragma unroll
      for (int ft = 0; ft < 4; ++ft)
        br[(i + 1) & 1][ft] = *(const bf16x8*)(wp + (ft >> 1) * 16384 +
                                               (ft & 1) * 512 + ktn * 1024);
    }
    const int sk = (ktp * 32 + quad * 8) ^ msk;
#pragma unroll
    for (int rb = 0; rb < 2; ++rb) {
      bf16x8 hv = *(const bf16x8*)&hb[(mRow0 + rb * 16 + c) * HDIM + sk];
#pragma unroll
      for (int ft = 0; ft < 4; ++ft)
        accM[rb][ft] = __builtin_amdgcn_mfma_f32_16x16x32_bf16(br[i & 1][ft], hv, accM[rb][ft], 0, 0, 0);
    }
    if (DO_EPI && (i & 1)) {
      const int e = i >> 1;           // 0..7, compile-time (unrolled)
      const int ft_e = e & 3, rb_e = e >> 2;
      const f32x4 bi = *(const f32x4*)&biasE[w * 64 + ft_e * 16 + quad * 4];
      bf16x4 pk;
#pragma unroll
      for (int j = 0; j < 4; ++j)
        pk[j] = (__bf16)apply_act<ACT>(accE[rb_e][ft_e][j] + bi[j]);
      const int fsw = (w * 64 + ft_e * 16 + quad * 4) ^ msk;
      *(bf16x4*)&hb[(eRow0 + rb_e * 16 + c) * HDIM + fsw] = pk;
    }
  }
}

// ---- drain the final half's epilogue (no pass left to host it) -------------
template <int ACT>
__device__ __forceinline__ void epi_burst(const float* __restrict__ biasE,
                                          __bf16* hb, const f32x4 (&accE)[2][4],
                                          const int eRow0, int w, int c,
                                          int quad) {
  const int msk = (c & 7) << 3;
#pragma unroll
  for (int e = 0; e < 8; ++e) {
    const int ft_e = e & 3, rb_e = e >> 2;
    const f32x4 bi = *(const f32x4*)&biasE[w * 64 + ft_e * 16 + quad * 4];
    bf16x4 pk;
#pragma unroll
    for (int j = 0; j < 4; ++j)
      pk[j] = (__bf16)apply_act<ACT>(accE[rb_e][ft_e][j] + bi[j]);
    const int fsw = (w * 64 + ft_e * 16 + quad * 4) ^ msk;
    *(bf16x4*)&hb[(eRow0 + rb_e * 16 + c) * HDIM + fsw] = pk;
  }
}

// ---- layer0: ysb(LDS) -> hbuf, both halves (caller syncs after) ------------
template <int ACT>
__device__ __forceinline__ void dense_l0(const __bf16* __restrict__ pw,
                                         const float* __restrict__ b0,
                                         const __bf16* __restrict__ ys,
                                         __bf16* hb, int w, int c, int quad,
                                         int lane) {
  bf16x8 aw[4];
#pragma unroll
  for (int ft = 0; ft < 4; ++ft)
    aw[ft] = *(const bf16x8*)&pw[(size_t)(w * 2 + (ft >> 1)) * 1024 +
                                 (ft & 1) * 512 + lane * 8];
  f32x4 acc[4][4];
#pragma unroll
  for (int rb = 0; rb < 4; ++rb)
#pragma unroll
    for (int ft = 0; ft < 4; ++ft) acc[rb][ft] = (f32x4){0.f, 0.f, 0.f, 0.f};
  const int ysk = (quad * 8) ^ ((c & 3) << 3);
#pragma unroll
  for (int rb = 0; rb < 4; ++rb) {
    bf16x8 yb = *(const bf16x8*)&ys[(rb * 16 + c) * 32 + ysk];
#pragma unroll
    for (int ft = 0; ft < 4; ++ft)
      acc[rb][ft] = __builtin_amdgcn_mfma_f32_16x16x32_bf16(aw[ft], yb, acc[rb][ft], 0, 0, 0);
  }
  const int msk = (c & 7) << 3;
#pragma unroll
  for (int ft = 0; ft < 4; ++ft) {
    const f32x4 bi = *(const f32x4*)&b0[w * 64 + ft * 16 + quad * 4];
    const int fsw = (w * 64 + ft * 16 + quad * 4) ^ msk;
#pragma unroll
    for (int rb = 0; rb < 4; ++rb) {
      bf16x4 pk;
#pragma unroll
      for (int i = 0; i < 4; ++i)
        pk[i] = (__bf16)apply_act<ACT>(acc[rb][ft][i] + bi[i]);
      *(bf16x4*)&hb[(rb * 16 + c) * HDIM + fsw] = pk;
    }
  }
}

// ---- head: hbuf -> per-lane f32x4 (bias added); fb=w&1, rb=w>>1 (0..3) -----
__device__ __forceinline__ f32x4 dense_head(const __bf16* __restrict__ ph,
                                            const float* __restrict__ bo,
                                            const __bf16* __restrict__ hb,
                                            int fb, int rb, int c, int quad,
                                            int lane) {
  const __bf16* wp = ph + (size_t)fb * 8192 + lane * 8;
  bf16x8 hr[3];
  hr[0] = *(const bf16x8*)wp;
  hr[1] = *(const bf16x8*)(wp + 512);
  f32x4 acc = (f32x4){0.f, 0.f, 0.f, 0.f};
  const int msk = (c & 7) << 3;
#pragma unroll
  for (int kt = 0; kt < 16; ++kt) {
    if (kt + 2 < 16) hr[(kt + 2) % 3] = *(const bf16x8*)(wp + (kt + 2) * 512);
    bf16x8 hv = *(const bf16x8*)&hb[(rb * 16 + c) * HDIM + ((kt * 32 + quad * 8) ^ msk)];
    acc = __builtin_amdgcn_mfma_f32_16x16x32_bf16(hr[kt % 3], hv, acc, 0, 0, 0);
  }
  const int f0 = fb * 16 + quad * 4;
  f32x4 bo4 = *(const f32x4*)&bo[f0];
#pragma unroll
  for (int i = 0; i < 4; ++i) acc[i] += bo4[i];
  return acc;
}

// ---- one full MLP net: l0 + 3 hidden (row-split pipelined) + head ----------
template <int ACT>
__device__ __forceinline__ f32x4 run_net(const __bf16* __restrict__ pw,
                                         const float* __restrict__ b0,
                                         const float* __restrict__ bh,
                                         const float* __restrict__ bo,
                                         const __bf16* __restrict__ ysb,
                                         __bf16* hbuf, int w, int fb, int rb,
                                         int c, int quad, int lane) {
  dense_l0<ACT>(pw, b0, ysb, hbuf, w, c, quad, lane);
  __syncthreads();
  f32x4 aA[2][4], aB[2][4];
  const __bf16* W1 = pw + PACK_H;
  const __bf16* W2 = pw + PACK_H + 262144;
  const __bf16* W3 = pw + PACK_H + 2 * 262144;
  // A1: MFMA L1 half0
  hidden_pass<ACT, false, false>(W1, nullptr, hbuf, aA, aB, 0, 32, w, c, quad, lane);
  __syncthreads();
  // B1: MFMA L1 half1 || epi L1 half0 (b1)
  hidden_pass<ACT, true, true>(W1, bh, hbuf, aB, aA, 32, 0, w, c, quad, lane);
  __syncthreads();
  // A2: MFMA L2 half0 || epi L1 half1 (b1)
  hidden_pass<ACT, false, true>(W2, bh, hbuf, aA, aB, 0, 32, w, c, quad, lane);
  __syncthreads();
  // B2: MFMA L2 half1 || epi L2 half0 (b2)
  hidden_pass<ACT, true, true>(W2, bh + 512, hbuf, aB, aA, 32, 0, w, c, quad, lane);
  __syncthreads();
  // A3: MFMA L3 half0 || epi L2 half1 (b2)
  hidden_pass<ACT, false, true>(W3, bh + 512, hbuf, aA, aB, 0, 32, w, c, quad, lane);
  __syncthreads();
  // B3: MFMA L3 half1 || epi L3 half0 (b3)
  hidden_pass<ACT, true, true>(W3, bh + 1024, hbuf, aB, aA, 32, 0, w, c, quad, lane);
  __syncthreads();
  // drain epi L3 half1 (b3)
  epi_burst<ACT>(bh + 1024, hbuf, aB, 32, w, c, quad);
  __syncthreads();
  return dense_head(pw + PACK_HEAD, bo, hbuf, fb, rb, c, quad, lane);
}

// ---- fully-fused coupling block: t-net + s-net + coupling + BN stats -------
template <bool FIRST>
__global__ __launch_bounds__(512, 4) void fused_block(
    const float* __restrict__ src, const __bf16* __restrict__ pwS,
    const __bf16* __restrict__ pwT, const float* __restrict__ sb0,
    const float* __restrict__ sbh, const float* __restrict__ sbo,
    const float* __restrict__ tb0, const float* __restrict__ tbh,
    const float* __restrict__ tbo, const float* __restrict__ prevP,
    float* __restrict__ zbuf, float* __restrict__ ld,
    float* __restrict__ stats_out, int o) {
  __shared__ __bf16 hbuf[WROWS * HDIM];      // 64 KiB
  __shared__ __bf16 ysb[WROWS * 32];         // 4 KiB
  const int tid = threadIdx.x;
  const int w = tid >> 6, lane = tid & 63, c = lane & 15, quad = lane >> 4;
  const size_t row0 = (size_t)blockIdx.x * WROWS;

  // stage normalized ys once: 64 rows x 32 cols
  {
    const int row = tid >> 3, sub = tid & 7;
    const int col0 = o + sub * 4;
    f32x4 yv = *(const f32x4*)&src[(row0 + row) * 64 + col0];
    bf16x4 pv;
#pragma unroll
    for (int j = 0; j < 4; ++j) {
      const float A_ = FIRST ? 1.f : prevP[col0 + j];
      const float C_ = FIRST ? 0.f : prevP[64 + col0 + j];
      pv[j] = (__bf16)fmaf(A_, yv[j], C_);
    }
    *(bf16x4*)&ysb[row * 32 + ((sub * 4) ^ ((row & 3) << 3))] = pv;
  }
  __syncthreads();

  const int fb = w & 1, rb = w >> 1;      // head/combine tile: 2 fb x 4 rb
  const int f0 = fb * 16 + quad * 4;
  const int r = rb * 16 + c;              // 0..63

  // ---- t-net (relu); tv stays in registers through the s-net ----
  f32x4 tv = run_net<2>(pwT, tb0, tbh, tbo, ysb, hbuf, w, fb, rb, c, quad, lane);
  __syncthreads();  // t-head hbuf reads done -> s-net may overwrite hbuf

  // ---- s-net (tanh) ----
  f32x4 sacc = run_net<1>(pwS, sb0, sbh, sbo, ysb, hbuf, w, fb, rb, c, quad, lane);
  float sv[4];
#pragma unroll
  for (int i = 0; i < 4; ++i) sv[i] = sacc[i];

  const size_t grow = row0 + r;
  __syncthreads();            // s-head hbuf reads done; reuse hbuf as scratch
  float* cs = (float*)hbuf;   // [128]: col sum | col sumsq
  float* lda = cs + 128;      // [64]: per-row logdet partials
  if (tid < 128) cs[tid] = 0.f;
  else if (tid < 192) lda[tid - 128] = 0.f;
  __syncthreads();

  const int oc = o ^ 32;
  float zc[4], yn2[4];
  {
    f32x4 pA1, pC1, pA2, pC2;
    if (FIRST) {
      pA1 = pA2 = (f32x4){1.f, 1.f, 1.f, 1.f};
      pC1 = pC2 = (f32x4){0.f, 0.f, 0.f, 0.f};
    } else {
      pA1 = *(const f32x4*)&prevP[oc + f0];
      pC1 = *(const f32x4*)&prevP[64 + oc + f0];
      pA2 = *(const f32x4*)&prevP[o + f0];
      pC2 = *(const f32x4*)&prevP[64 + o + f0];
    }
    f32x4 yv = *(const f32x4*)&src[grow * 64 + oc + f0];
    f32x4 zo;
#pragma unroll
    for (int i = 0; i < 4; ++i) {
      zc[i] = fmaf(fmaf(pA1[i], yv[i], pC1[i]), __expf(sv[i]), tv[i]);
      zo[i] = zc[i];
    }
    *(f32x4*)&zbuf[grow * 64 + oc + f0] = zo;
    f32x4 yv2 = *(const f32x4*)&src[grow * 64 + o + f0];
    f32x4 yo;
#pragma unroll
    for (int i = 0; i < 4; ++i) {
      yn2[i] = fmaf(pA2[i], yv2[i], pC2[i]);
      yo[i] = yn2[i];
    }
    *(f32x4*)&zbuf[grow * 64 + o + f0] = yo;
  }

  // per-row logdet partial
  {
    float ssum = sv[0] + sv[1] + sv[2] + sv[3];
    ssum += __shfl_xor(ssum, 16);
    ssum += __shfl_xor(ssum, 32);
    if (quad == 0) atomicAdd(&lda[r], ssum);
  }

  // column stats: reduce over the 16 c-lanes, then LDS atomics
#pragma unroll
  for (int i = 0; i < 4; ++i) {
    float v = zc[i], q = zc[i] * zc[i];
    float v2 = yn2[i], q2 = yn2[i] * yn2[i];
#pragma unroll
    for (int m = 1; m < 16; m <<= 1) {
      v += __shfl_xor(v, m);  q += __shfl_xor(q, m);
      v2 += __shfl_xor(v2, m); q2 += __shfl_xor(q2, m);
    }
    if (c == 0) {
      atomicAdd(&cs[oc + f0 + i], v);
      atomicAdd(&cs[64 + oc + f0 + i], q);
      atomicAdd(&cs[o + f0 + i], v2);
      atomicAdd(&cs[64 + o + f0 + i], q2);
    }
  }
  __syncthreads();
  if (tid < 128) {
    atomicAdd(&stats_out[tid], cs[tid]);
  } else if (tid < 192) {
    const int rr = tid - 128;
    const size_t gr = row0 + rr;
    if (FIRST) ld[gr] = lda[rr]; else ld[gr] += lda[rr];
  }
}

// ---- small kernels ----------------------------------------------------------

__global__ void stats_kernel(const float* __restrict__ raw,
                             const float* __restrict__ lg,
                             const float* __restrict__ beta,
                             float* __restrict__ param,
                             float* __restrict__ ld_scalar) {
  const int t = threadIdx.x;  // 64
  const float S = raw[t], SS = raw[64 + t];
  const float mean = S / (float)BROWS;
  const float var = (SS - S * mean) / (float)(BROWS - 1);
  const float inv = rsqrtf(var + EPSV);
  const float g = __expf(lg[t]);
  const float A = g * inv;
  param[t] = A;
  param[64 + t] = beta[t] - mean * A;
  float contrib = lg[t] - 0.5f * __logf(var + EPSV);
  contrib += __shfl_xor(contrib, 1);  contrib += __shfl_xor(contrib, 2);
  contrib += __shfl_xor(contrib, 4);  contrib += __shfl_xor(contrib, 8);
  contrib += __shfl_xor(contrib, 16); contrib += __shfl_xor(contrib, 32);
  if (t == 0) atomicAdd(ld_scalar, contrib);
}

__global__ void final_kernel(float* __restrict__ out,
                             const float* __restrict__ param7,
                             const float* __restrict__ ld_scalar) {
  const size_t gid = (size_t)blockIdx.x * 256 + threadIdx.x;
  const size_t total = (size_t)BROWS * 64;
  const int col = gid & 63;
  const float z = out[gid];
  out[gid] = param7[col] * z + param7[64 + col];
  if (gid < BROWS) out[total + gid] += ld_scalar[0];
}

// ---- pack weights: A-operand fragment streams (layout unchanged) -----------
__global__ void pack_weights(const float* __restrict__ sW0,
                             const float* __restrict__ sWh,
                             const float* __restrict__ sWo,
                             const float* __restrict__ tW0,
                             const float* __restrict__ tWh,
                             const float* __restrict__ tWo,
                             __bf16* __restrict__ dst) {
  const int gid = blockIdx.x * 256 + threadIdx.x;
  const int gpn = PACK_NET / 8;
  const int b = gid / (2 * gpn);
  const int rr0 = gid % (2 * gpn);
  const int net = rr0 / gpn;
  const size_t o = (size_t)(rr0 % gpn) * 8;
  const float* W0 = net ? tW0 : sW0;
  const float* Wh = net ? tWh : sWh;
  const float* Wo = net ? tWo : sWo;
  __bf16* d = dst + ((size_t)b * 2 + net) * PACK_NET + o;
  float v[8];
  if (o < PACK_H) {  // l0: K=32
    const int idx = (int)(o >> 3);
    const int lane = idx & 63, fbb = (idx >> 6) & 1, w = (idx >> 7) & 15;
    const int cc = lane & 15, q = lane >> 4;
    const int f = w * 32 + fbb * 16 + cc;
    const float* s = W0 + (size_t)b * 32 * 512;
#pragma unroll
    for (int j = 0; j < 8; ++j) v[j] = s[(size_t)(q * 8 + j) * 512 + f];
  } else if (o < PACK_HEAD) {  // hidden
    const size_t oo = o - PACK_H;
    const int l = (int)(oo >> 18);
    const int idx = (int)((oo & 262143) >> 3);
    const int lane = idx & 63, fbb = (idx >> 6) & 1, kt = (idx >> 7) & 15,
              w = (idx >> 11) & 15;
    const int cc = lane & 15, q = lane >> 4;
    const int f = w * 32 + fbb * 16 + cc;
    const float* s = Wh + ((size_t)(b * 3 + l)) * 512 * 512;
#pragma unroll
    for (int j = 0; j < 8; ++j) v[j] = s[(size_t)(kt * 32 + q * 8 + j) * 512 + f];
  } else {  // head
    const size_t oo = o - PACK_HEAD;
    const int idx = (int)(oo >> 3);
    const int lane = idx & 63, kt = (idx >> 6) & 15, fbb = (idx >> 10) & 1;
    const int cc = lane & 15, q = lane >> 4;
    const int f = fbb * 16 + cc;
    const float* s = Wo + (size_t)b * 512 * 32;
#pragma unroll
    for (int j = 0; j < 8; ++j) v[j] = s[(size_t)(kt * 32 + q * 8 + j) * 32 + f];
  }
  bf16x8 pv;
#pragma unroll
  for (int j = 0; j < 8; ++j) pv[j] = (__bf16)v[j];
  *(bf16x8*)d = pv;
}

// ---- launcher ---------------------------------------------------------------

extern "C" void kernel_launch(void* const* d_in, const int* in_sizes, int n_in,
                              void* d_out, int out_size, void* d_ws, size_t ws_size,
                              hipStream_t stream) {
  const float* y_in = (const float*)d_in[0];
  const float* sW0 = (const float*)d_in[1];
  const float* sb0 = (const float*)d_in[2];
  const float* sWh = (const float*)d_in[3];
  const float* sbh = (const float*)d_in[4];
  const float* sWo = (const float*)d_in[5];
  const float* sbo = (const float*)d_in[6];
  const float* tW0 = (const float*)d_in[7];
  const float* tb0 = (const float*)d_in[8];
  const float* tWh = (const float*)d_in[9];
  const float* tbh = (const float*)d_in[10];
  const float* tWo = (const float*)d_in[11];
  const float* tbo = (const float*)d_in[12];
  const float* bn_lg = (const float*)d_in[13];
  const float* bn_bt = (const float*)d_in[14];

  char* p = (char*)d_ws;
  __bf16* packed = (__bf16*)p; p += (size_t)NBLK * 2 * PACK_NET * 2;  // 256B-mult
  float* stats_raw = (float*)p; p += NBLK * 128 * 4;
  float* ld_scalar = (float*)p; p += 256;   // padded: keeps stats_param 256B-aligned
  float* stats_param = (float*)p; p += NBLK * 128 * 4;

  float* out = (float*)d_out;
  float* zbuf = out;
  float* ld = out + (size_t)BROWS * 64;

  pack_weights<<<(NBLK * 2 * PACK_NET / 8) / 256, 256, 0, stream>>>(
      sW0, sWh, sWo, tW0, tWh, tWo, packed);
  hipMemsetAsync(stats_raw, 0, NBLK * 128 * 4 + 256, stream);

  const int GG = BROWS / WROWS;  // 2048 wgs of 512 threads; 2 WGs/CU

  for (int b = 0; b < NBLK; ++b) {
    const int o = (b & 1) ? 32 : 0;
    const __bf16* pwS = packed + (size_t)b * 2 * PACK_NET;
    const __bf16* pwT = pwS + PACK_NET;
    float* praw = stats_raw + b * 128;
    const float* srcb = (b == 0) ? y_in : zbuf;

    if (b == 0) {
      fused_block<true><<<GG, 512, 0, stream>>>(srcb, pwS, pwT,
          sb0, sbh, sbo, tb0, tbh, tbo, nullptr, zbuf, ld, praw, o);
    } else {
      fused_block<false><<<GG, 512, 0, stream>>>(srcb, pwS, pwT,
          sb0 + b * 512, sbh + (size_t)b * 1536, sbo + b * 32,
          tb0 + b * 512, tbh + (size_t)b * 1536, tbo + b * 32,
          stats_param + (size_t)(b - 1) * 128, zbuf, ld, praw, o);
    }
    stats_kernel<<<1, 64, 0, stream>>>(praw, bn_lg + b * 64, bn_bt + b * 64,
                                       stats_param + (size_t)b * 128, ld_scalar);
  }

  final_kernel<<<(BROWS * 64) / 256, 256, 0, stream>>>(
      out, stats_param + 7 * 128, ld_scalar);
}

// Round 4
// 3913.226 us; speedup vs baseline: 5.6033x; 5.6033x over previous
//
#include <hip/hip_runtime.h>

#define NBLK 8
#define BROWS 131072
#define HDIM 512
#define EPSV 1e-5f
#define WROWS 64

typedef __bf16 bf16x8 __attribute__((ext_vector_type(8)));
typedef __bf16 bf16x4 __attribute__((ext_vector_type(4)));
typedef float f32x4 __attribute__((ext_vector_type(4)));

// packed net stream (elems): l0 16384 | 3 hidden x 262144 | head 16384
// layouts (unchanged; reinterpreted at use site):
//   l0     [w16][fb2][lane64][8]
//   hidden [w16][kt16][fb2][lane64][8]
//   head   [fb2][kt16][lane64][8]
#define PACK_NET 819200
#define PACK_H 16384
#define PACK_HEAD 802816

__device__ __forceinline__ float act_tanh_f(float x) {
  float e = __expf(x + x);
  return fmaf(-2.f, __builtin_amdgcn_rcpf(e + 1.f), 1.f);
}

template <int ACT>
__device__ __forceinline__ float apply_act(float v) {
  if (ACT == 1) return act_tanh_f(v);
  return fmaxf(v, 0.f);
}

// ---- hidden layer, operand-swapped, 8 waves x (64 feat x 64 rows), in place
// NOTE: kt ascends for every wave/WG — concurrent WGs share the weight slab
// in L2 by temporal alignment. Do not reorder (R3 lesson: reverse order
// dropped weight L2 residency -> 10x HBM traffic, 5x slowdown).
template <int ACT>
__device__ __forceinline__ void dense_hidden(const __bf16* __restrict__ Wp,
                                             const float* __restrict__ bias,
                                             __bf16* hb, int w, int c,
                                             int quad, int lane) {
  f32x4 acc[4][4];  // [rb(16-row block)][ft(16-feature tile)]
#pragma unroll
  for (int rb = 0; rb < 4; ++rb)
#pragma unroll
    for (int ft = 0; ft < 4; ++ft) acc[rb][ft] = (f32x4){0.f, 0.f, 0.f, 0.f};
  // feature tile t = w*4+ft lives at (t>>1)*16384 + (t&1)*512
  const __bf16* wp = Wp + (size_t)(w * 2) * 16384 + lane * 8;
  bf16x8 br[3][4];  // 2-deep prefetch: ~320cy cover for L2-miss spikes
#pragma unroll
  for (int s = 0; s < 2; ++s)
#pragma unroll
    for (int ft = 0; ft < 4; ++ft)
      br[s][ft] = *(const bf16x8*)(wp + (ft >> 1) * 16384 + (ft & 1) * 512 +
                                   s * 1024);
  const int msk = (c & 7) << 3;
  __builtin_amdgcn_s_setprio(1);  // favor MFMA-phase waves over epilogue-phase
#pragma unroll
  for (int kt = 0; kt < 16; ++kt) {
    if (kt + 2 < 16) {
#pragma unroll
      for (int ft = 0; ft < 4; ++ft)
        br[(kt + 2) % 3][ft] = *(const bf16x8*)(wp + (ft >> 1) * 16384 +
                                                (ft & 1) * 512 + (kt + 2) * 1024);
    }
    const int sk = (kt * 32 + quad * 8) ^ msk;
#pragma unroll
    for (int rb = 0; rb < 4; ++rb) {
      bf16x8 hv = *(const bf16x8*)&hb[(rb * 16 + c) * HDIM + sk];
#pragma unroll
      for (int ft = 0; ft < 4; ++ft)
        acc[rb][ft] = __builtin_amdgcn_mfma_f32_16x16x32_bf16(br[kt % 3][ft], hv, acc[rb][ft], 0, 0, 0);
    }
  }
  __builtin_amdgcn_s_setprio(0);
  __syncthreads();  // all hbuf reads done -> safe to overwrite in place
#pragma unroll
  for (int ft = 0; ft < 4; ++ft) {
    const f32x4 bi = *(const f32x4*)&bias[w * 64 + ft * 16 + quad * 4];
    const int fsw = (w * 64 + ft * 16 + quad * 4) ^ msk;
#pragma unroll
    for (int rb = 0; rb < 4; ++rb) {
      bf16x4 pk;
#pragma unroll
      for (int i = 0; i < 4; ++i)
        pk[i] = (__bf16)apply_act<ACT>(acc[rb][ft][i] + bi[i]);
      *(bf16x4*)&hb[(rb * 16 + c) * HDIM + fsw] = pk;
    }
  }
  __syncthreads();
}

// ---- layer0: ysb(LDS) -> hbuf (caller must sync after) ---------------------
template <int ACT>
__device__ __forceinline__ void dense_l0(const __bf16* __restrict__ pw,
                                         const float* __restrict__ b0,
                                         const __bf16* __restrict__ ys,
                                         __bf16* hb, int w, int c, int quad,
                                         int lane) {
  bf16x8 aw[4];
#pragma unroll
  for (int ft = 0; ft < 4; ++ft)
    aw[ft] = *(const bf16x8*)&pw[(size_t)(w * 2 + (ft >> 1)) * 1024 +
                                 (ft & 1) * 512 + lane * 8];
  f32x4 acc[4][4];
#pragma unroll
  for (int rb = 0; rb < 4; ++rb)
#pragma unroll
    for (int ft = 0; ft < 4; ++ft) acc[rb][ft] = (f32x4){0.f, 0.f, 0.f, 0.f};
  const int ysk = (quad * 8) ^ ((c & 3) << 3);
  __builtin_amdgcn_s_setprio(1);
#pragma unroll
  for (int rb = 0; rb < 4; ++rb) {
    bf16x8 yb = *(const bf16x8*)&ys[(rb * 16 + c) * 32 + ysk];
#pragma unroll
    for (int ft = 0; ft < 4; ++ft)
      acc[rb][ft] = __builtin_amdgcn_mfma_f32_16x16x32_bf16(aw[ft], yb, acc[rb][ft], 0, 0, 0);
  }
  __builtin_amdgcn_s_setprio(0);
  const int msk = (c & 7) << 3;
#pragma unroll
  for (int ft = 0; ft < 4; ++ft) {
    const f32x4 bi = *(const f32x4*)&b0[w * 64 + ft * 16 + quad * 4];
    const int fsw = (w * 64 + ft * 16 + quad * 4) ^ msk;
#pragma unroll
    for (int rb = 0; rb < 4; ++rb) {
      bf16x4 pk;
#pragma unroll
      for (int i = 0; i < 4; ++i)
        pk[i] = (__bf16)apply_act<ACT>(acc[rb][ft][i] + bi[i]);
      *(bf16x4*)&hb[(rb * 16 + c) * HDIM + fsw] = pk;
    }
  }
}

// ---- head: hbuf -> per-lane f32x4 (bias added); fb=w&1, rb=w>>1 (0..3) -----
__device__ __forceinline__ f32x4 dense_head(const __bf16* __restrict__ ph,
                                            const float* __restrict__ bo,
                                            const __bf16* __restrict__ hb,
                                            int fb, int rb, int c, int quad,
                                            int lane) {
  const __bf16* wp = ph + (size_t)fb * 8192 + lane * 8;
  bf16x8 hr[3];
  hr[0] = *(const bf16x8*)wp;
  hr[1] = *(const bf16x8*)(wp + 512);
  f32x4 acc = (f32x4){0.f, 0.f, 0.f, 0.f};
  const int msk = (c & 7) << 3;
  __builtin_amdgcn_s_setprio(1);
#pragma unroll
  for (int kt = 0; kt < 16; ++kt) {
    if (kt + 2 < 16) hr[(kt + 2) % 3] = *(const bf16x8*)(wp + (kt + 2) * 512);
    bf16x8 hv = *(const bf16x8*)&hb[(rb * 16 + c) * HDIM + ((kt * 32 + quad * 8) ^ msk)];
    acc = __builtin_amdgcn_mfma_f32_16x16x32_bf16(hr[kt % 3], hv, acc, 0, 0, 0);
  }
  __builtin_amdgcn_s_setprio(0);
  const int f0 = fb * 16 + quad * 4;
  f32x4 bo4 = *(const f32x4*)&bo[f0];
#pragma unroll
  for (int i = 0; i < 4; ++i) acc[i] += bo4[i];
  return acc;
}

// ---- fully-fused coupling block: t-net + s-net + coupling + BN stats -------
template <bool FIRST>
__global__ __launch_bounds__(512, 4) void fused_block(
    const float* __restrict__ src, const __bf16* __restrict__ pwS,
    const __bf16* __restrict__ pwT, const float* __restrict__ sb0,
    const float* __restrict__ sbh, const float* __restrict__ sbo,
    const float* __restrict__ tb0, const float* __restrict__ tbh,
    const float* __restrict__ tbo, const float* __restrict__ prevP,
    float* __restrict__ zbuf, float* __restrict__ ld,
    float* __restrict__ stats_out, int o) {
  __shared__ __bf16 hbuf[WROWS * HDIM];      // 64 KiB
  __shared__ __bf16 ysb[WROWS * 32];         // 4 KiB
  __shared__ float tout[WROWS * 36];         // 9 KiB (t-head stash)
  const int tid = threadIdx.x;
  const int w = tid >> 6, lane = tid & 63, c = lane & 15, quad = lane >> 4;
  const size_t row0 = (size_t)blockIdx.x * WROWS;

  // stage normalized ys once: 64 rows x 32 cols
  {
    const int row = tid >> 3, sub = tid & 7;
    const int col0 = o + sub * 4;
    f32x4 yv = *(const f32x4*)&src[(row0 + row) * 64 + col0];
    bf16x4 pv;
#pragma unroll
    for (int j = 0; j < 4; ++j) {
      const float A_ = FIRST ? 1.f : prevP[col0 + j];
      const float C_ = FIRST ? 0.f : prevP[64 + col0 + j];
      pv[j] = (__bf16)fmaf(A_, yv[j], C_);
    }
    *(bf16x4*)&ysb[row * 32 + ((sub * 4) ^ ((row & 3) << 3))] = pv;
  }
  __syncthreads();

  const int fb = w & 1, rb = w >> 1;      // head/combine tile: 2 fb x 4 rb
  const int f0 = fb * 16 + quad * 4;
  const int r = rb * 16 + c;              // 0..63

  // ---- t-net (relu) ----
  dense_l0<2>(pwT, tb0, ysb, hbuf, w, c, quad, lane);
  __syncthreads();
  dense_hidden<2>(pwT + PACK_H, tbh, hbuf, w, c, quad, lane);
  dense_hidden<2>(pwT + PACK_H + 262144, tbh + 512, hbuf, w, c, quad, lane);
  dense_hidden<2>(pwT + PACK_H + 2 * 262144, tbh + 1024, hbuf, w, c, quad, lane);
  {
    f32x4 tvh = dense_head(pwT + PACK_HEAD, tbo, hbuf, fb, rb, c, quad, lane);
    *(f32x4*)&tout[r * 36 + f0] = tvh;
  }
  __syncthreads();  // t-head hbuf reads + tout writes complete

  // ---- s-net (tanh) ----
  dense_l0<1>(pwS, sb0, ysb, hbuf, w, c, quad, lane);
  __syncthreads();
  dense_hidden<1>(pwS + PACK_H, sbh, hbuf, w, c, quad, lane);
  dense_hidden<1>(pwS + PACK_H + 262144, sbh + 512, hbuf, w, c, quad, lane);
  dense_hidden<1>(pwS + PACK_H + 2 * 262144, sbh + 1024, hbuf, w, c, quad, lane);
  f32x4 sacc = dense_head(pwS + PACK_HEAD, sbo, hbuf, fb, rb, c, quad, lane);
  float sv[4];
#pragma unroll
  for (int i = 0; i < 4; ++i) sv[i] = sacc[i];

  const size_t grow = row0 + r;
  f32x4 tv = *(const f32x4*)&tout[r * 36 + f0];
  __syncthreads();            // s-head hbuf reads done; reuse hbuf as scratch
  float* cs = (float*)hbuf;   // [128]: col sum | col sumsq
  float* lda = cs + 128;      // [64]: per-row logdet partials
  if (tid < 128) cs[tid] = 0.f;
  else if (tid < 192) lda[tid - 128] = 0.f;
  __syncthreads();

  const int oc = o ^ 32;
  float zc[4], yn2[4];
  {
    f32x4 pA1, pC1, pA2, pC2;
    if (FIRST) {
      pA1 = pA2 = (f32x4){1.f, 1.f, 1.f, 1.f};
      pC1 = pC2 = (f32x4){0.f, 0.f, 0.f, 0.f};
    } else {
      pA1 = *(const f32x4*)&prevP[oc + f0];
      pC1 = *(const f32x4*)&prevP[64 + oc + f0];
      pA2 = *(const f32x4*)&prevP[o + f0];
      pC2 = *(const f32x4*)&prevP[64 + o + f0];
    }
    f32x4 yv = *(const f32x4*)&src[grow * 64 + oc + f0];
    f32x4 zo;
#pragma unroll
    for (int i = 0; i < 4; ++i) {
      zc[i] = fmaf(fmaf(pA1[i], yv[i], pC1[i]), __expf(sv[i]), tv[i]);
      zo[i] = zc[i];
    }
    *(f32x4*)&zbuf[grow * 64 + oc + f0] = zo;
    f32x4 yv2 = *(const f32x4*)&src[grow * 64 + o + f0];
    f32x4 yo;
#pragma unroll
    for (int i = 0; i < 4; ++i) {
      yn2[i] = fmaf(pA2[i], yv2[i], pC2[i]);
      yo[i] = yn2[i];
    }
    *(f32x4*)&zbuf[grow * 64 + o + f0] = yo;
  }

  // per-row logdet partial
  {
    float ssum = sv[0] + sv[1] + sv[2] + sv[3];
    ssum += __shfl_xor(ssum, 16);
    ssum += __shfl_xor(ssum, 32);
    if (quad == 0) atomicAdd(&lda[r], ssum);
  }

  // column stats: reduce over the 16 c-lanes, then LDS atomics
#pragma unroll
  for (int i = 0; i < 4; ++i) {
    float v = zc[i], q = zc[i] * zc[i];
    float v2 = yn2[i], q2 = yn2[i] * yn2[i];
#pragma unroll
    for (int m = 1; m < 16; m <<= 1) {
      v += __shfl_xor(v, m);  q += __shfl_xor(q, m);
      v2 += __shfl_xor(v2, m); q2 += __shfl_xor(q2, m);
    }
    if (c == 0) {
      atomicAdd(&cs[oc + f0 + i], v);
      atomicAdd(&cs[64 + oc + f0 + i], q);
      atomicAdd(&cs[o + f0 + i], v2);
      atomicAdd(&cs[64 + o + f0 + i], q2);
    }
  }
  __syncthreads();
  if (tid < 128) {
    atomicAdd(&stats_out[tid], cs[tid]);
  } else if (tid < 192) {
    const int rr = tid - 128;
    const size_t gr = row0 + rr;
    if (FIRST) ld[gr] = lda[rr]; else ld[gr] += lda[rr];
  }
}

// ---- small kernels ----------------------------------------------------------

__global__ void stats_kernel(const float* __restrict__ raw,
                             const float* __restrict__ lg,
                             const float* __restrict__ beta,
                             float* __restrict__ param,
                             float* __restrict__ ld_scalar) {
  const int t = threadIdx.x;  // 64
  const float S = raw[t], SS = raw[64 + t];
  const float mean = S / (float)BROWS;
  const float var = (SS - S * mean) / (float)(BROWS - 1);
  const float inv = rsqrtf(var + EPSV);
  const float g = __expf(lg[t]);
  const float A = g * inv;
  param[t] = A;
  param[64 + t] = beta[t] - mean * A;
  float contrib = lg[t] - 0.5f * __logf(var + EPSV);
  contrib += __shfl_xor(contrib, 1);  contrib += __shfl_xor(contrib, 2);
  contrib += __shfl_xor(contrib, 4);  contrib += __shfl_xor(contrib, 8);
  contrib += __shfl_xor(contrib, 16); contrib += __shfl_xor(contrib, 32);
  if (t == 0) atomicAdd(ld_scalar, contrib);
}

__global__ void final_kernel(float* __restrict__ out,
                             const float* __restrict__ param7,
                             const float* __restrict__ ld_scalar) {
  const size_t gid = (size_t)blockIdx.x * 256 + threadIdx.x;
  const size_t total = (size_t)BROWS * 64;
  const int col = gid & 63;
  const float z = out[gid];
  out[gid] = param7[col] * z + param7[64 + col];
  if (gid < BROWS) out[total + gid] += ld_scalar[0];
}

// ---- pack weights: A-operand fragment streams (layout unchanged) -----------
__global__ void pack_weights(const float* __restrict__ sW0,
                             const float* __restrict__ sWh,
                             const float* __restrict__ sWo,
                             const float* __restrict__ tW0,
                             const float* __restrict__ tWh,
                             const float* __restrict__ tWo,
                             __bf16* __restrict__ dst) {
  const int gid = blockIdx.x * 256 + threadIdx.x;
  const int gpn = PACK_NET / 8;
  const int b = gid / (2 * gpn);
  const int rr0 = gid % (2 * gpn);
  const int net = rr0 / gpn;
  const size_t o = (size_t)(rr0 % gpn) * 8;
  const float* W0 = net ? tW0 : sW0;
  const float* Wh = net ? tWh : sWh;
  const float* Wo = net ? tWo : sWo;
  __bf16* d = dst + ((size_t)b * 2 + net) * PACK_NET + o;
  float v[8];
  if (o < PACK_H) {  // l0: K=32
    const int idx = (int)(o >> 3);
    const int lane = idx & 63, fbb = (idx >> 6) & 1, w = (idx >> 7) & 15;
    const int cc = lane & 15, q = lane >> 4;
    const int f = w * 32 + fbb * 16 + cc;
    const float* s = W0 + (size_t)b * 32 * 512;
#pragma unroll
    for (int j = 0; j < 8; ++j) v[j] = s[(size_t)(q * 8 + j) * 512 + f];
  } else if (o < PACK_HEAD) {  // hidden
    const size_t oo = o - PACK_H;
    const int l = (int)(oo >> 18);
    const int idx = (int)((oo & 262143) >> 3);
    const int lane = idx & 63, fbb = (idx >> 6) & 1, kt = (idx >> 7) & 15,
              w = (idx >> 11) & 15;
    const int cc = lane & 15, q = lane >> 4;
    const int f = w * 32 + fbb * 16 + cc;
    const float* s = Wh + ((size_t)(b * 3 + l)) * 512 * 512;
#pragma unroll
    for (int j = 0; j < 8; ++j) v[j] = s[(size_t)(kt * 32 + q * 8 + j) * 512 + f];
  } else {  // head
    const size_t oo = o - PACK_HEAD;
    const int idx = (int)(oo >> 3);
    const int lane = idx & 63, kt = (idx >> 6) & 15, fbb = (idx >> 10) & 1;
    const int cc = lane & 15, q = lane >> 4;
    const int f = fbb * 16 + cc;
    const float* s = Wo + (size_t)b * 512 * 32;
#pragma unroll
    for (int j = 0; j < 8; ++j) v[j] = s[(size_t)(kt * 32 + q * 8 + j) * 32 + f];
  }
  bf16x8 pv;
#pragma unroll
  for (int j = 0; j < 8; ++j) pv[j] = (__bf16)v[j];
  *(bf16x8*)d = pv;
}

// ---- launcher ---------------------------------------------------------------

extern "C" void kernel_launch(void* const* d_in, const int* in_sizes, int n_in,
                              void* d_out, int out_size, void* d_ws, size_t ws_size,
                              hipStream_t stream) {
  const float* y_in = (const float*)d_in[0];
  const float* sW0 = (const float*)d_in[1];
  const float* sb0 = (const float*)d_in[2];
  const float* sWh = (const float*)d_in[3];
  const float* sbh = (const float*)d_in[4];
  const float* sWo = (const float*)d_in[5];
  const float* sbo = (const float*)d_in[6];
  const float* tW0 = (const float*)d_in[7];
  const float* tb0 = (const float*)d_in[8];
  const float* tWh = (const float*)d_in[9];
  const float* tbh = (const float*)d_in[10];
  const float* tWo = (const float*)d_in[11];
  const float* tbo = (const float*)d_in[12];
  const float* bn_lg = (const float*)d_in[13];
  const float* bn_bt = (const float*)d_in[14];

  char* p = (char*)d_ws;
  __bf16* packed = (__bf16*)p; p += (size_t)NBLK * 2 * PACK_NET * 2;  // 256B-mult
  float* stats_raw = (float*)p; p += NBLK * 128 * 4;
  float* ld_scalar = (float*)p; p += 256;   // padded: keeps stats_param 256B-aligned
  float* stats_param = (float*)p; p += NBLK * 128 * 4;

  float* out = (float*)d_out;
  float* zbuf = out;
  float* ld = out + (size_t)BROWS * 64;

  pack_weights<<<(NBLK * 2 * PACK_NET / 8) / 256, 256, 0, stream>>>(
      sW0, sWh, sWo, tW0, tWh, tWo, packed);
  hipMemsetAsync(stats_raw, 0, NBLK * 128 * 4 + 256, stream);

  const int GG = BROWS / WROWS;  // 2048 wgs of 512 threads; 2 WGs/CU

  for (int b = 0; b < NBLK; ++b) {
    const int o = (b & 1) ? 32 : 0;
    const __bf16* pwS = packed + (size_t)b * 2 * PACK_NET;
    const __bf16* pwT = pwS + PACK_NET;
    float* praw = stats_raw + b * 128;
    const float* srcb = (b == 0) ? y_in : zbuf;

    if (b == 0) {
      fused_block<true><<<GG, 512, 0, stream>>>(srcb, pwS, pwT,
          sb0, sbh, sbo, tb0, tbh, tbo, nullptr, zbuf, ld, praw, o);
    } else {
      fused_block<false><<<GG, 512, 0, stream>>>(srcb, pwS, pwT,
          sb0 + b * 512, sbh + (size_t)b * 1536, sbo + b * 32,
          tb0 + b * 512, tbh + (size_t)b * 1536, tbo + b * 32,
          stats_param + (size_t)(b - 1) * 128, zbuf, ld, praw, o);
    }
    stats_kernel<<<1, 64, 0, stream>>>(praw, bn_lg + b * 64, bn_bt + b * 64,
                                       stats_param + (size_t)b * 128, ld_scalar);
  }

  final_kernel<<<(BROWS * 64) / 256, 256, 0, stream>>>(
      out, stats_param + 7 * 128, ld_scalar);
}